// Round 1
// baseline (242.237 us; speedup 1.0000x reference)
//
#include <hip/hip_runtime.h>

#define NB 16
#define NC 256
#define NHW 784
#define NATN 16
#define NM 12544          // 16*784
#define ND 256
#define NTRI 32896        // 256*257/2
#define ATT_OUT_OFF 526336
#define SPLITK 4

typedef float f32x4 __attribute__((ext_vector_type(4)));
typedef short bf16x8 __attribute__((ext_vector_type(8)));

static __device__ __forceinline__ unsigned short f2bf(float f) {
  unsigned int u = __float_as_uint(f);
  u = (u + 0x7FFFu + ((u >> 16) & 1u)) >> 16;   // RNE
  return (unsigned short)u;
}

#define GLD16(g, l) __builtin_amdgcn_global_load_lds(                      \
    (const __attribute__((address_space(1))) void*)(g),                    \
    (__attribute__((address_space(3))) void*)(l), 16, 0, 0)

// ---------------- attentions = sigmoid(raw) + eps ----------------
__global__ void k_attn(const float* __restrict__ raw, float* __restrict__ out_att,
                       float* __restrict__ att_ws) {
  int i = blockIdx.x * 256 + threadIdx.x;
  if (i < NB * NATN * NHW) {
    float v = raw[i];
    float a = 1.0f / (1.0f + __expf(-v)) + 1e-12f;
    out_att[i] = a;
    att_ws[i]  = a;
  }
}

// ---------------- z = attn * x  (bf16) + row sums ----------------
__global__ void k_z(const float* __restrict__ x, const float* __restrict__ att,
                    unsigned short* __restrict__ z, float* __restrict__ s) {
  int bc = blockIdx.x;                 // b*256 + c
  int b  = bc >> 8;
  int tid = threadIdx.x;
  const float* xr = x + (size_t)bc * NHW;
  unsigned short* zr = z + (size_t)bc * NM;
  float sum = 0.f;
  for (int a = 0; a < NATN; ++a) {
    const float* ar = att + (size_t)(b * NATN + a) * NHW;
    for (int hw = tid; hw < NHW; hw += 256) {
      float v = ar[hw] * xr[hw];
      zr[a * NHW + hw] = f2bf(v);
      sum += v;
    }
  }
  for (int off = 32; off; off >>= 1) sum += __shfl_down(sum, off, 64);
  __shared__ float red[4];
  if ((tid & 63) == 0) red[tid >> 6] = sum;
  __syncthreads();
  if (tid == 0) s[bc] = red[0] + red[1] + red[2] + red[3];
}

// ---------------- cov GEMM: P[split][b] += z_tile * z_tile^T ----------------
// 128x128 tiles, BK=64, 4 waves, split-K=4. Only tiles (0,0),(0,1),(1,1) (G symmetric).
__global__ __launch_bounds__(256)
void k_cov(const unsigned short* __restrict__ z, float* __restrict__ P) {
  int bid = blockIdx.x;
  int split = bid & 3;
  int t3 = (bid >> 2) % 3;
  int b = bid / 12;
  int tm = (t3 == 2) ? 1 : 0;
  int tn = (t3 >= 1) ? 1 : 0;

  __shared__ __align__(16) unsigned short As[128 * 64];
  __shared__ __align__(16) unsigned short Bs[128 * 64];

  int tid = threadIdx.x;
  int lane = tid & 63, w = tid >> 6;
  int wm = w >> 1, wn = w & 1;
  int fr = lane & 15, kg = lane >> 4;

  const unsigned short* zb = z + (size_t)b * NC * NM;
  const unsigned short* ab = zb + (size_t)(tm * 128 + (tid >> 3)) * NM + (size_t)(tid & 7) * 8;
  const unsigned short* bb = zb + (size_t)(tn * 128 + (tid >> 3)) * NM + (size_t)(tid & 7) * 8;

  f32x4 acc[4][4];
#pragma unroll
  for (int i = 0; i < 4; ++i)
#pragma unroll
    for (int j = 0; j < 4; ++j) acc[i][j] = f32x4{0.f, 0.f, 0.f, 0.f};

  int k0 = split * (NM / SPLITK);
  char* AsB = (char*)As + (size_t)w * 1024;
  char* BsB = (char*)Bs + (size_t)w * 1024;

  for (int kt = 0; kt < (NM / SPLITK) / 64; ++kt) {   // 49 iters
    int kb = k0 + kt * 64;
#pragma unroll
    for (int r = 0; r < 4; ++r) GLD16(ab + (size_t)r * 32 * NM + kb, AsB + r * 4096);
#pragma unroll
    for (int r = 0; r < 4; ++r) GLD16(bb + (size_t)r * 32 * NM + kb, BsB + r * 4096);
    __syncthreads();
#pragma unroll
    for (int kk = 0; kk < 2; ++kk) {
      bf16x8 av[4], bv[4];
#pragma unroll
      for (int fm = 0; fm < 4; ++fm)
        av[fm] = *(const bf16x8*)&As[(wm * 64 + fm * 16 + fr) * 64 + kk * 32 + kg * 8];
#pragma unroll
      for (int fn = 0; fn < 4; ++fn)
        bv[fn] = *(const bf16x8*)&Bs[(wn * 64 + fn * 16 + fr) * 64 + kk * 32 + kg * 8];
#pragma unroll
      for (int fm = 0; fm < 4; ++fm)
#pragma unroll
        for (int fn = 0; fn < 4; ++fn)
          acc[fm][fn] = __builtin_amdgcn_mfma_f32_16x16x32_bf16(av[fm], bv[fn], acc[fm][fn], 0, 0, 0);
    }
    __syncthreads();
  }

  float* Pb = P + (size_t)(split * NB + b) * (ND * ND);
#pragma unroll
  for (int fm = 0; fm < 4; ++fm)
#pragma unroll
    for (int fn = 0; fn < 4; ++fn)
#pragma unroll
      for (int ri = 0; ri < 4; ++ri) {
        int row = tm * 128 + wm * 64 + fm * 16 + kg * 4 + ri;
        int col = tn * 128 + wn * 64 + fn * 16 + fr;
        Pb[row * ND + col] = acc[fm][fn][ri];
      }
}

// ---------------- cov = (sum P)/M - s s^T / M^2  (mirror tile (1,0)) ----------------
__global__ void k_asm(const float* __restrict__ P, const float* __restrict__ s,
                      float* __restrict__ cov) {
  int i = blockIdx.x * 256 + threadIdx.x;
  int b = i >> 16;
  int rc = i & 65535;
  int r = rc >> 8, c = rc & 255;
  int rr = r, cc = c;
  if (r >= 128 && c < 128) { rr = c; cc = r; }   // tile (1,0) never computed; use (0,1)
  int prc = rr * ND + cc;
  const float invM = 1.0f / 12544.0f;
  float g = P[(size_t)(0 * NB + b) * 65536 + prc] + P[(size_t)(1 * NB + b) * 65536 + prc] +
            P[(size_t)(2 * NB + b) * 65536 + prc] + P[(size_t)(3 * NB + b) * 65536 + prc];
  float sr = s[b * NC + r], sc2 = s[b * NC + c];
  cov[i] = g * invM - sr * sc2 * (invM * invM);
}

// ---------------- normA = trace(cov), sqrt ----------------
__global__ void k_trace(const float* __restrict__ cov, float* __restrict__ nrm,
                        float* __restrict__ sqn) {
  int b = blockIdx.x, tid = threadIdx.x;
  float v = cov[(size_t)b * 65536 + tid * 257];
  for (int off = 32; off; off >>= 1) v += __shfl_down(v, off, 64);
  __shared__ float red[4];
  if ((tid & 63) == 0) red[tid >> 6] = v;
  __syncthreads();
  if (tid == 0) {
    float n = red[0] + red[1] + red[2] + red[3];
    nrm[b] = n;
    sqn[b] = sqrtf(n);
  }
}

// ---------------- An = cov/normA (bf16); Z0 = 1.5I - 0.5 An (bf16) ----------------
__global__ void k_anzy(const float* __restrict__ cov, const float* __restrict__ nrm,
                       unsigned short* __restrict__ An, unsigned short* __restrict__ Z) {
  int i = blockIdx.x * 256 + threadIdx.x;
  int b = i >> 16;
  int rc = i & 65535;
  int r = rc >> 8, c = rc & 255;
  float a = cov[i] / nrm[b];
  An[i] = f2bf(a);
  Z[i]  = f2bf((r == c ? 1.5f : 0.0f) - 0.5f * a);
}

// ---------------- NS matmul: C = A*B (B symmetric -> NT). MODE1: C = 1.5I - 0.5*A*B ----------------
// 64x64 tiles, BK=64, 4 waves (each 32x32). Dual-dispatch via blockIdx.y.
template <int MODE>
__global__ __launch_bounds__(256)
void k_ns(const unsigned short* __restrict__ A0, const unsigned short* __restrict__ B0,
          unsigned short* __restrict__ C0,
          const unsigned short* __restrict__ A1, const unsigned short* __restrict__ B1,
          unsigned short* __restrict__ C1) {
  const unsigned short* A  = blockIdx.y ? A1 : A0;
  const unsigned short* Bm = blockIdx.y ? B1 : B0;
  unsigned short* Cm       = blockIdx.y ? C1 : C0;
  int bid = blockIdx.x;
  int tile = bid & 15, b = bid >> 4;
  int tm = tile >> 2, tn = tile & 3;

  __shared__ __align__(16) unsigned short As[64 * 64];
  __shared__ __align__(16) unsigned short Bs[64 * 64];

  int tid = threadIdx.x, lane = tid & 63, w = tid >> 6;
  int wm = w >> 1, wn = w & 1;
  int fr = lane & 15, kg = lane >> 4;

  const unsigned short* ab = A  + (size_t)b * ND * ND + (size_t)(tm * 64 + (tid >> 3)) * ND + (size_t)(tid & 7) * 8;
  const unsigned short* bb = Bm + (size_t)b * ND * ND + (size_t)(tn * 64 + (tid >> 3)) * ND + (size_t)(tid & 7) * 8;
  char* AsB = (char*)As + (size_t)w * 1024;
  char* BsB = (char*)Bs + (size_t)w * 1024;

  f32x4 acc[2][2];
#pragma unroll
  for (int i = 0; i < 2; ++i)
#pragma unroll
    for (int j = 0; j < 2; ++j) acc[i][j] = f32x4{0.f, 0.f, 0.f, 0.f};

  for (int kt = 0; kt < 4; ++kt) {
#pragma unroll
    for (int r = 0; r < 2; ++r) {
      GLD16(ab + (size_t)r * 32 * ND + kt * 64, AsB + r * 4096);
      GLD16(bb + (size_t)r * 32 * ND + kt * 64, BsB + r * 4096);
    }
    __syncthreads();
#pragma unroll
    for (int kk = 0; kk < 2; ++kk) {
      bf16x8 av[2], bv[2];
#pragma unroll
      for (int fm = 0; fm < 2; ++fm)
        av[fm] = *(const bf16x8*)&As[(wm * 32 + fm * 16 + fr) * 64 + kk * 32 + kg * 8];
#pragma unroll
      for (int fn = 0; fn < 2; ++fn)
        bv[fn] = *(const bf16x8*)&Bs[(wn * 32 + fn * 16 + fr) * 64 + kk * 32 + kg * 8];
#pragma unroll
      for (int fm = 0; fm < 2; ++fm)
#pragma unroll
        for (int fn = 0; fn < 2; ++fn)
          acc[fm][fn] = __builtin_amdgcn_mfma_f32_16x16x32_bf16(av[fm], bv[fn], acc[fm][fn], 0, 0, 0);
    }
    __syncthreads();
  }

  unsigned short* Cb = Cm + (size_t)b * ND * ND;
#pragma unroll
  for (int fm = 0; fm < 2; ++fm)
#pragma unroll
    for (int fn = 0; fn < 2; ++fn)
#pragma unroll
      for (int ri = 0; ri < 4; ++ri) {
        int row = tm * 64 + wm * 32 + fm * 16 + kg * 4 + ri;
        int col = tn * 64 + wn * 32 + fn * 16 + fr;
        float v = acc[fm][fn][ri];
        if (MODE == 1) v = (row == col ? 1.5f : 0.0f) - 0.5f * v;
        Cb[row * ND + col] = f2bf(v);
      }
}

// ---------------- final: out = triuvec(Y @ ZY) * sqrt(normA) ----------------
__global__ __launch_bounds__(256)
void k_final(const unsigned short* __restrict__ Y, const unsigned short* __restrict__ ZY,
             const float* __restrict__ sqn, float* __restrict__ out) {
  const int tmv[10] = {0, 1, 2, 3, 5, 6, 7, 10, 11, 15};  // upper-tri 64x64 tiles only
  int bid = blockIdx.x;
  int t = bid % 10, b = bid / 10;
  int tile = tmv[t];
  int tm = tile >> 2, tn = tile & 3;

  __shared__ __align__(16) unsigned short As[64 * 64];
  __shared__ __align__(16) unsigned short Bs[64 * 64];

  int tid = threadIdx.x, lane = tid & 63, w = tid >> 6;
  int wm = w >> 1, wn = w & 1;
  int fr = lane & 15, kg = lane >> 4;

  const unsigned short* ab = Y  + (size_t)b * ND * ND + (size_t)(tm * 64 + (tid >> 3)) * ND + (size_t)(tid & 7) * 8;
  const unsigned short* bb = ZY + (size_t)b * ND * ND + (size_t)(tn * 64 + (tid >> 3)) * ND + (size_t)(tid & 7) * 8;
  char* AsB = (char*)As + (size_t)w * 1024;
  char* BsB = (char*)Bs + (size_t)w * 1024;

  f32x4 acc[2][2];
#pragma unroll
  for (int i = 0; i < 2; ++i)
#pragma unroll
    for (int j = 0; j < 2; ++j) acc[i][j] = f32x4{0.f, 0.f, 0.f, 0.f};

  for (int kt = 0; kt < 4; ++kt) {
#pragma unroll
    for (int r = 0; r < 2; ++r) {
      GLD16(ab + (size_t)r * 32 * ND + kt * 64, AsB + r * 4096);
      GLD16(bb + (size_t)r * 32 * ND + kt * 64, BsB + r * 4096);
    }
    __syncthreads();
#pragma unroll
    for (int kk = 0; kk < 2; ++kk) {
      bf16x8 av[2], bv[2];
#pragma unroll
      for (int fm = 0; fm < 2; ++fm)
        av[fm] = *(const bf16x8*)&As[(wm * 32 + fm * 16 + fr) * 64 + kk * 32 + kg * 8];
#pragma unroll
      for (int fn = 0; fn < 2; ++fn)
        bv[fn] = *(const bf16x8*)&Bs[(wn * 32 + fn * 16 + fr) * 64 + kk * 32 + kg * 8];
#pragma unroll
      for (int fm = 0; fm < 2; ++fm)
#pragma unroll
        for (int fn = 0; fn < 2; ++fn)
          acc[fm][fn] = __builtin_amdgcn_mfma_f32_16x16x32_bf16(av[fm], bv[fn], acc[fm][fn], 0, 0, 0);
    }
    __syncthreads();
  }

  float sc = sqn[b];
#pragma unroll
  for (int fm = 0; fm < 2; ++fm)
#pragma unroll
    for (int fn = 0; fn < 2; ++fn)
#pragma unroll
      for (int ri = 0; ri < 4; ++ri) {
        int row = tm * 64 + wm * 32 + fm * 16 + kg * 4 + ri;
        int col = tn * 64 + wn * 32 + fn * 16 + fr;
        if (row <= col) {
          int idx = row * ND - (row * (row - 1)) / 2 + (col - row);
          out[(size_t)b * NTRI + idx] = acc[fm][fn][ri] * sc;
        }
      }
}

extern "C" void kernel_launch(void* const* d_in, const int* in_sizes, int n_in,
                              void* d_out, int out_size, void* d_ws, size_t ws_size,
                              hipStream_t stream) {
  const float* x   = (const float*)d_in[0];
  const float* raw = (const float*)d_in[1];
  float* out = (float*)d_out;
  char* ws = (char*)d_ws;

  const size_t Z_OFF   = 0;
  const size_t ATT_OFF = Z_OFF + (size_t)NB * NC * NM * 2;        // 102,760,448
  const size_t S_OFF   = ATT_OFF + (size_t)NB * NATN * NHW * 4;   // + 802,816
  const size_t P_OFF   = S_OFF + (size_t)NB * NC * 4;             // + 16,384
  const size_t COV_OFF = P_OFF + (size_t)SPLITK * NB * ND * ND * 4;  // + 16,777,216
  const size_t NA_OFF  = COV_OFF + (size_t)NB * ND * ND * 4;      // + 4,194,304
  const size_t SQ_OFF  = NA_OFF + 64;
  const size_t AN_OFF  = SQ_OFF + 64;
  const size_t MATB    = (size_t)NB * ND * ND * 2;                // 2,097,152
  const size_t Y_OFF   = AN_OFF + MATB;
  const size_t ZM_OFF  = Y_OFF + MATB;
  const size_t ZY_OFF  = ZM_OFF + MATB;
  const size_t Y2_OFF  = ZY_OFF + MATB;
  const size_t Z2_OFF  = Y2_OFF + MATB;

  unsigned short* z   = (unsigned short*)(ws + Z_OFF);
  float* att  = (float*)(ws + ATT_OFF);
  float* ssum = (float*)(ws + S_OFF);
  float* P    = (float*)(ws + P_OFF);
  float* cov  = (float*)(ws + COV_OFF);
  float* nrm  = (float*)(ws + NA_OFF);
  float* sqn  = (float*)(ws + SQ_OFF);
  unsigned short* An  = (unsigned short*)(ws + AN_OFF);
  unsigned short* Yb  = (unsigned short*)(ws + Y_OFF);
  unsigned short* Zb  = (unsigned short*)(ws + ZM_OFF);
  unsigned short* ZYb = (unsigned short*)(ws + ZY_OFF);
  unsigned short* Y2b = (unsigned short*)(ws + Y2_OFF);
  unsigned short* Z2b = (unsigned short*)(ws + Z2_OFF);

  k_attn<<<NB * NATN * NHW / 256, 256, 0, stream>>>(raw, out + ATT_OUT_OFF, att);
  k_z<<<NB * NC, 256, 0, stream>>>(x, att, z, ssum);
  k_cov<<<NB * 3 * SPLITK, 256, 0, stream>>>(z, P);
  k_asm<<<NB * ND * ND / 256, 256, 0, stream>>>(P, ssum, cov);
  k_trace<<<NB, 256, 0, stream>>>(cov, nrm, sqn);
  k_anzy<<<NB * ND * ND / 256, 256, 0, stream>>>(cov, nrm, An, Zb);

  // Y1 = An @ ZY0   (ZY0 stored in Zb)
  k_ns<0><<<dim3(256, 1), 256, 0, stream>>>(An, Zb, Yb, An, Zb, Yb);

  unsigned short *Yc = Yb, *Zc = Zb, *Yn = Y2b, *Zn = Z2b;
  for (int it = 0; it < 3; ++it) {
    k_ns<1><<<dim3(256, 1), 256, 0, stream>>>(Zc, Yc, ZYb, Zc, Yc, ZYb);      // ZY = 1.5I - 0.5 Z@Y
    k_ns<0><<<dim3(256, 2), 256, 0, stream>>>(Yc, ZYb, Yn, ZYb, Zc, Zn);      // Y'=Y@ZY ; Z'=ZY@Z
    unsigned short* t;
    t = Yc; Yc = Yn; Yn = t;
    t = Zc; Zc = Zn; Zn = t;
  }
  k_ns<1><<<dim3(256, 1), 256, 0, stream>>>(Zc, Yc, ZYb, Zc, Yc, ZYb);        // final ZY
  k_final<<<160, 256, 0, stream>>>(Yc, ZYb, sqn, out);                        // triuvec(Y@ZY)*sqrt(normA)
}